// Round 3
// baseline (220.409 us; speedup 1.0000x reference)
//
#include <hip/hip_runtime.h>

// BoostedNeuralLDPCDecoder — MI355X HIP implementation (round 3)
//
// Round-3 changes vs round 2 (194.7 us; kernels latency-bound, not BW-bound):
//  * init no longer copies tot / zeroes c2v: cn(it=0) reads xa directly
//    (permuted gather) and skips the c2v load (c2v==0 at it0). init only
//    zeroes the 24 KB dummy row + builds tables.
//  * cn_kernel processes 2 batches per block (grid 46x32): 16 independent
//    belief loads in flight, scalar edge loads amortized, half the blocks.
//  * vn_kernel: c2v re-encoded as biased uint8 (2*msg+32, range [2,62]);
//    each thread covers 2 consecutive z via one ushort load per edge and
//    SWAR byte-lane accumulation -> half the gather VMEM instructions.
//    Integer sums remain exact (bias subtracted once; dummy row = 0x20).
//
// Layouts (lane = z => coalesced, incl. shifted circulant access):
//   tot  [N][B][Z] float      (6.68 MB)
//   c2v  [E+1][B][Z] uint8    (9.07 MB)  value = 2*msg+32 in [2,62]; row E = 32s
//   vn_deg[N], voff[N][24] (byte offsets e*B*Z; dummy = E*B*Z)

#define ITERS 5
#define Nn 68
#define Mm 46
#define Zz 384
#define Ee 368
#define Bb 64
#define Kk 8          // edges per CN (E/M)
#define PADD 24       // padded max VN degree
#define BIGF 1e9f

#define ROWB (Bb*Zz)                     // 24,576 bytes per c2v edge-row
#define TOT_ELEMS (Nn*Bb*Zz)             // 1,671,168 floats
#define C2V_BYTES ((Ee+1)*ROWB)          // 9,068,544 bytes (incl. dummy row)
#define TOT_OFF   0
#define C2V_OFF   (TOT_ELEMS*4)          // 6,684,672
#define DEG_OFF   (C2V_OFF + C2V_BYTES)  // 15,753,216
#define VOFF_OFF  (DEG_OFF + 384)        // 15,753,600
// total ws need: VOFF_OFF + Nn*PADD*4 = 15,760,128 bytes (~15.8 MB)

__global__ __launch_bounds__(256) void init_kernel(
    const int* __restrict__ edge_vn, unsigned char* __restrict__ c2v,
    int* __restrict__ vn_deg, int* __restrict__ voff)
{
    if (blockIdx.x == 0) {
        // dummy row = biased zero (0x20 per byte); 24,576 B = 1536 int4
        int4* p = (int4*)(c2v + (size_t)Ee * ROWB);
        const int4 v = make_int4(0x20202020, 0x20202020, 0x20202020, 0x20202020);
        for (int i = threadIdx.x; i < ROWB / 16; i += 256) p[i] = v;
    } else {
        // padded per-VN offset table; LDS staging kills the load chain
        __shared__ int sev[Ee];
        for (int t = threadIdx.x; t < Ee; t += 256) sev[t] = edge_vn[t];
        __syncthreads();
        int n = threadIdx.x;
        if (n < Nn) {
            int d = 0;
            for (int e = 0; e < Ee; e++)
                if (sev[e] == n && d < PADD) voff[n * PADD + (d++)] = e * ROWB;
            vn_deg[n] = d;
            for (int j = d; j < PADD; j++) voff[n * PADD + j] = Ee * ROWB;
        }
    }
}

__global__ __launch_bounds__(384) void cn_kernel(
    const float* __restrict__ belief,    // xa (it==0, [B][N][Z]) or tot ([N][B][Z])
    unsigned char* __restrict__ c2v,
    const int* __restrict__ edge_vn, const int* __restrict__ edge_shift,
    const float* __restrict__ cn_weight, int it)
{
    const int cn = blockIdx.x;           // [0, M)
    const int b0 = blockIdx.y * 2;       // two batches per block
    const int zc = threadIdx.x;          // [0, Z) — CN-domain lifted row
    const float w = cn_weight[it];
    const bool it0 = (it == 0);

    float v[2][Kk];
    int   off[2][Kk];
    float m1[2] = {BIGF, BIGF};
    unsigned sf[2] = {0u, 0u};

    #pragma unroll
    for (int k = 0; k < Kk; k++) {
        int e  = cn + k * Mm;            // edges of this check (edge_cn = e % M)
        int sh = edge_shift[e];          // block-uniform -> scalar load
        int n  = edge_vn[e];             // block-uniform
        int z  = zc - sh;
        z += (z >> 31) & Zz;             // mod Z
        #pragma unroll
        for (int bb = 0; bb < 2; bb++) {
            int b = b0 + bb;
            int o = e * ROWB + b * Zz + z;
            off[bb][k] = o;
            float x;
            if (it0) {
                x = belief[(b * Nn + n) * Zz + z];          // tot==xa, c2v==0
            } else {
                float t = belief[(n * Bb + b) * Zz + z];
                x = t - 0.5f * (float)((int)c2v[o] - 32);   // exact decode
            }
            x = fminf(20.0f, fmaxf(-20.0f, x));             // allowed_llr_range
            v[bb][k] = x;
            sf[bb] ^= (x < 0.0f) ? 1u : 0u;
            m1[bb] = fminf(m1[bb], fabsf(x));
        }
    }

    #pragma unroll
    for (int bb = 0; bb < 2; bb++) {
        // min2 over entries whose |v| != min1 (reference tie semantics)
        float m2 = BIGF;
        #pragma unroll
        for (int k = 0; k < Kk; k++) {
            float mag = fabsf(v[bb][k]);
            if (mag != m1[bb]) m2 = fminf(m2, mag);
        }
        #pragma unroll
        for (int k = 0; k < Kk; k++) {
            float mag  = fabsf(v[bb][k]);
            float emin = (mag == m1[bb]) ? m2 : m1[bb];
            unsigned neg = sf[bb] ^ ((v[bb][k] < 0.0f) ? 1u : 0u);
            float ext = neg ? -emin : emin;
            // _qms5(w*ext): forward == clip(rintf(2x)/2, +-7.5); store biased 2q
            float r = rintf(w * ext * 2.0f);
            r = fminf(15.0f, fmaxf(-15.0f, r));
            c2v[off[bb][k]] = (unsigned char)((int)r + 32);
        }
    }
}

__global__ __launch_bounds__(256) void vn_kernel(
    const float* __restrict__ xa, const unsigned char* __restrict__ c2v,
    float* __restrict__ tot, float* __restrict__ out,
    const int* __restrict__ vn_deg, const int* __restrict__ voff,
    int write_tot)
{
    __shared__ float tile[9][130];       // [n_local][z_local], stride 130 (8B-align ok)
    const int b  = blockIdx.x;
    const int z0 = blockIdx.y * 128;
    const int n0 = blockIdx.z * 9;
    const int wave = threadIdx.x >> 6;
    const int lane = threadIdx.x & 63;
    const int z  = z0 + 2 * lane;        // this thread owns z, z+1
    const int bz = b * Zz + z;           // offset within a c2v edge-row

    for (int i = wave; i < 9; i += 4) {
        if (n0 + i >= Nn) break;                         // wave-uniform
        int n = __builtin_amdgcn_readfirstlane(n0 + i);  // force scalar table loads
        int d = vn_deg[n];                               // wave-uniform
        const int* vo = voff + n * PADD;
        int aL = 0, aH = 0, L = 8;       // SWAR byte-lane sums of (2*msg+32)
        #pragma unroll
        for (int j = 0; j < 8; j++) {
            unsigned u = *(const unsigned short*)(c2v + (vo[j] + bz));
            aL += u & 0xFFu; aH += u >> 8;
        }
        if (d > 8) {
            L = 16;
            #pragma unroll
            for (int j = 8; j < 16; j++) {
                unsigned u = *(const unsigned short*)(c2v + (vo[j] + bz));
                aL += u & 0xFFu; aH += u >> 8;
            }
            if (d > 16) {
                L = 24;
                #pragma unroll
                for (int j = 16; j < PADD; j++) {
                    unsigned u = *(const unsigned short*)(c2v + (vo[j] + bz));
                    aL += u & 0xFFu; aH += u >> 8;
                }
            }
        }
        // aL-32L = sum of 2*msg (dummies cancel): exact integer; one fp rounding
        float2 x = *(const float2*)(xa + ((size_t)b * Nn + n) * Zz + z);
        float sL = x.x + 0.5f * (float)(aL - 32 * L);
        float sH = x.y + 0.5f * (float)(aH - 32 * L);
        if (write_tot)
            *(float2*)(tot + (n * Bb + b) * Zz + z) = make_float2(sL, sH);
        *(float2*)&tile[i][2 * lane] = make_float2(sL, sH);
    }
    __syncthreads();

    // out[it][b][z][n]: block covers z in [z0,z0+128) x n in [n0,n0+9)
    float* dst = out + ((size_t)b * Zz + z0) * Nn + n0;
    const int nmax = (Nn - n0 < 9) ? (Nn - n0) : 9;
    for (int idx = threadIdx.x; idx < 128 * 9; idx += 256) {
        int zz = idx / 9;
        int nn = idx - zz * 9;
        if (nn < nmax) dst[(size_t)zz * Nn + nn] = tile[nn][zz];
    }
}

extern "C" void kernel_launch(void* const* d_in, const int* in_sizes, int n_in,
                              void* d_out, int out_size, void* d_ws, size_t ws_size,
                              hipStream_t stream) {
    const float* xa        = (const float*)d_in[0];  // [B][N][Z]
    const float* cn_weight = (const float*)d_in[1];  // [ITERS]
    const int*   edge_vn   = (const int*)d_in[2];    // [E]
    // d_in[3] = edge_cn: structurally e % M, not needed
    const int*   edge_shift= (const int*)d_in[4];    // [E]
    float* out = (float*)d_out;                      // [ITERS][B][Z][N]

    char* ws = (char*)d_ws;
    float*         tot    = (float*)(ws + TOT_OFF);
    unsigned char* c2v    = (unsigned char*)(ws + C2V_OFF);
    int*           vn_deg = (int*)(ws + DEG_OFF);
    int*           voff   = (int*)(ws + VOFF_OFF);

    init_kernel<<<2, 256, 0, stream>>>(edge_vn, c2v, vn_deg, voff);

    for (int it = 0; it < ITERS; it++) {
        const float* belief = (it == 0) ? xa : tot;
        cn_kernel<<<dim3(Mm, Bb / 2), 384, 0, stream>>>(belief, c2v, edge_vn,
                                                        edge_shift, cn_weight, it);
        vn_kernel<<<dim3(Bb, Zz / 128, 8), 256, 0, stream>>>(
            xa, c2v, tot, out + (size_t)it * Bb * Zz * Nn,
            vn_deg, voff, (it != ITERS - 1) ? 1 : 0);
    }
}

// Round 4
// 188.906 us; speedup vs baseline: 1.1668x; 1.1668x over previous
//
#include <hip/hip_runtime.h>

// BoostedNeuralLDPCDecoder — MI355X HIP implementation (round 4)
//
// Round 3 (2-batch cn + SWAR vn) regressed 194.7 -> 220.4 us; this round
// reverts to the measured round-2 kernel structure and keeps only the
// strictly-less-work change:
//  * cn0_kernel (it=0) reads xa directly ([B][N][Z] addressing) and skips
//    the c2v load entirely (c2v == 0 at it 0). Therefore init no longer
//    copies tot (22 MB) — it only zeroes the 24 KB dummy row + builds the
//    per-VN gather tables.
//
// Layouts (lane = z => coalesced, incl. shifted circulant access):
//   tot  [N][B][Z] float      (6.68 MB)
//   c2v  [E+1][B][Z] int8     (9.07 MB) value = 2*message in [-15,15]; row E = 0
//   vn_deg[N], voff[N][24] (byte offsets e*B*Z; dummy = E*B*Z)

#define ITERS 5
#define Nn 68
#define Mm 46
#define Zz 384
#define Ee 368
#define Bb 64
#define Kk 8          // edges per CN (E/M)
#define PADD 24       // padded max VN degree
#define BIGF 1e9f

#define ROWB (Bb*Zz)                     // 24,576 bytes per c2v edge-row
#define TOT_ELEMS (Nn*Bb*Zz)             // 1,671,168 floats
#define C2V_BYTES ((Ee+1)*ROWB)          // 9,068,544 bytes (incl. zero row)
#define TOT_OFF   0
#define C2V_OFF   (TOT_ELEMS*4)          // 6,684,672
#define DEG_OFF   (C2V_OFF + C2V_BYTES)  // 15,753,216
#define VOFF_OFF  (DEG_OFF + 384)        // 15,753,600
// total ws need: VOFF_OFF + Nn*PADD*4 = 15,760,128 bytes (~15.8 MB)

__global__ __launch_bounds__(256) void init_kernel(
    const int* __restrict__ edge_vn, signed char* __restrict__ c2v,
    int* __restrict__ vn_deg, int* __restrict__ voff)
{
    if (blockIdx.x == 0) {
        // dummy row = zeros; 24,576 B = 1536 int4
        int4* p = (int4*)(c2v + (size_t)Ee * ROWB);
        for (int i = threadIdx.x; i < ROWB / 16; i += 256)
            p[i] = make_int4(0, 0, 0, 0);
    } else {
        // padded per-VN offset table; LDS staging kills the load chain
        __shared__ int sev[Ee];
        for (int t = threadIdx.x; t < Ee; t += 256) sev[t] = edge_vn[t];
        __syncthreads();
        int n = threadIdx.x;
        if (n < Nn) {
            int d = 0;
            for (int e = 0; e < Ee; e++)
                if (sev[e] == n && d < PADD) voff[n * PADD + (d++)] = e * ROWB;
            vn_deg[n] = d;
            for (int j = d; j < PADD; j++) voff[n * PADD + j] = Ee * ROWB; // zero row
        }
    }
}

// Shared min-sum tail: given extrinsic inputs v[8] (clamped), write quantized
// messages. Kept as a macro-ish inline so cn0/cn stay identical here.
__device__ __forceinline__ void minsum_store(
    const float v[Kk], const int off[Kk], float m1, unsigned sflip,
    float w, signed char* __restrict__ c2v)
{
    // min2 over entries whose |v| != min1 (reference tie semantics, BIG if none)
    float m2 = BIGF;
    #pragma unroll
    for (int k = 0; k < Kk; k++) {
        float mag = fabsf(v[k]);
        if (mag != m1) m2 = fminf(m2, mag);
    }
    #pragma unroll
    for (int k = 0; k < Kk; k++) {
        float mag  = fabsf(v[k]);
        float emin = (mag == m1) ? m2 : m1;
        unsigned neg = sflip ^ ((v[k] < 0.0f) ? 1u : 0u);  // csign * own_sign
        float ext = neg ? -emin : emin;
        // _qms5(w * ext): forward == clip(rintf(2*x)/2, +-7.5); store 2*q as int8
        float r = rintf(w * ext * 2.0f);
        r = fminf(15.0f, fmaxf(-15.0f, r));
        c2v[off[k]] = (signed char)(int)r;
    }
}

__global__ __launch_bounds__(384) void cn0_kernel(
    const float* __restrict__ xa,        // [B][N][Z]; tot==xa, c2v==0 at it 0
    signed char* __restrict__ c2v,
    const int* __restrict__ edge_vn, const int* __restrict__ edge_shift,
    const float* __restrict__ cn_weight)
{
    const int cn = blockIdx.x;
    const int b  = blockIdx.y;
    const int zc = threadIdx.x;
    const float w = cn_weight[0];

    float v[Kk];
    int   off[Kk];
    float m1 = BIGF;
    unsigned sflip = 0u;

    #pragma unroll
    for (int k = 0; k < Kk; k++) {
        int e  = cn + k * Mm;
        int sh = edge_shift[e];          // block-uniform -> scalar load
        int n  = edge_vn[e];             // block-uniform
        int z  = zc - sh;
        z += (z >> 31) & Zz;             // mod Z
        off[k] = e * ROWB + b * Zz + z;
        float x = xa[(b * Nn + n) * Zz + z];      // belief; no c2v subtract at it 0
        x = fminf(20.0f, fmaxf(-20.0f, x));       // allowed_llr_range
        v[k] = x;
        if (x < 0.0f) sflip ^= 1u;
        m1 = fminf(m1, fabsf(x));
    }
    minsum_store(v, off, m1, sflip, w, c2v);
}

__global__ __launch_bounds__(384) void cn_kernel(
    const float* __restrict__ tot, signed char* __restrict__ c2v,
    const int* __restrict__ edge_vn, const int* __restrict__ edge_shift,
    const float* __restrict__ cn_weight, int it)
{
    const int cn = blockIdx.x;       // [0, M)
    const int b  = blockIdx.y;       // [0, B)
    const int zc = threadIdx.x;      // [0, Z) — CN-domain lifted row
    const float w = cn_weight[it];

    float v[Kk];
    int   off[Kk];
    float m1 = BIGF;
    unsigned sflip = 0u;

    #pragma unroll
    for (int k = 0; k < Kk; k++) {
        int e  = cn + k * Mm;        // edges of this check (edge_cn = e % M)
        int sh = edge_shift[e];      // block-uniform -> scalar load
        int n  = edge_vn[e];         // block-uniform
        int z  = zc - sh;
        z += (z >> 31) & Zz;         // mod Z
        int o = e * ROWB + b * Zz + z;
        off[k] = o;
        float t = tot[(n * Bb + b) * Zz + z];     // VN belief at VN-domain row z
        float c = 0.5f * (float)c2v[o];           // exact decode
        float x = t - c;                          // extrinsic (one rounding, = ref)
        x = fminf(20.0f, fmaxf(-20.0f, x));       // allowed_llr_range
        v[k] = x;
        if (x < 0.0f) sflip ^= 1u;
        m1 = fminf(m1, fabsf(x));
    }
    minsum_store(v, off, m1, sflip, w, c2v);
}

__global__ __launch_bounds__(256) void vn_kernel(
    const float* __restrict__ xa, const signed char* __restrict__ c2v,
    float* __restrict__ tot, float* __restrict__ out,
    const int* __restrict__ vn_deg, const int* __restrict__ voff,
    int write_tot)
{
    __shared__ float tile[17][65];   // [n_local][z_local+1 pad] — conflict-free
    const int b  = blockIdx.x;
    const int z0 = blockIdx.y * 64;
    const int n0 = blockIdx.z * 17;
    const int wave = threadIdx.x >> 6;
    const int lane = threadIdx.x & 63;
    const int z = z0 + lane;
    const int bz = b * Zz + z;       // offset within a c2v edge-row

    for (int i = wave; i < 17; i += 4) {
        int n = __builtin_amdgcn_readfirstlane(n0 + i);  // force scalar table loads
        int d = vn_deg[n];                               // wave-uniform
        const int* vo = voff + n * PADD;
        int acc = 0;                 // sum of int8 messages (2x value): exact
        #pragma unroll
        for (int j = 0; j < 8; j++) acc += (int)c2v[vo[j] + bz];   // 8 indep loads
        if (d > 8) {
            #pragma unroll
            for (int j = 8; j < 16; j++) acc += (int)c2v[vo[j] + bz];
        }
        if (d > 16) {
            #pragma unroll
            for (int j = 16; j < PADD; j++) acc += (int)c2v[vo[j] + bz];
        }
        float s = xa[(size_t)(b * Nn + n) * Zz + z] + 0.5f * (float)acc; // one rounding
        if (write_tot) tot[(n * Bb + b) * Zz + z] = s;   // belief for next iteration
        tile[i][lane] = s;
    }
    __syncthreads();

    // out[it][b][z][n]: this block covers z in [z0,z0+64) x n in [n0,n0+17)
    // -> 64 contiguous 68B segments; L2 merges the 4 n-chunk blocks' segments.
    float* dst = out + ((size_t)b * Zz + z0) * Nn + n0;
    for (int idx = threadIdx.x; idx < 17 * 64; idx += 256) {
        int zz = idx / 17;
        int nn = idx - zz * 17;
        dst[(size_t)zz * Nn + nn] = tile[nn][zz];
    }
}

extern "C" void kernel_launch(void* const* d_in, const int* in_sizes, int n_in,
                              void* d_out, int out_size, void* d_ws, size_t ws_size,
                              hipStream_t stream) {
    const float* xa        = (const float*)d_in[0];  // [B][N][Z]
    const float* cn_weight = (const float*)d_in[1];  // [ITERS]
    const int*   edge_vn   = (const int*)d_in[2];    // [E]
    // d_in[3] = edge_cn: structurally e % M, not needed
    const int*   edge_shift= (const int*)d_in[4];    // [E]
    float* out = (float*)d_out;                      // [ITERS][B][Z][N]

    char* ws = (char*)d_ws;
    float*       tot    = (float*)(ws + TOT_OFF);
    signed char* c2v    = (signed char*)(ws + C2V_OFF);
    int*         vn_deg = (int*)(ws + DEG_OFF);
    int*         voff   = (int*)(ws + VOFF_OFF);

    init_kernel<<<2, 256, 0, stream>>>(edge_vn, c2v, vn_deg, voff);

    for (int it = 0; it < ITERS; it++) {
        if (it == 0)
            cn0_kernel<<<dim3(Mm, Bb), 384, 0, stream>>>(xa, c2v, edge_vn,
                                                         edge_shift, cn_weight);
        else
            cn_kernel<<<dim3(Mm, Bb), 384, 0, stream>>>(tot, c2v, edge_vn,
                                                        edge_shift, cn_weight, it);
        vn_kernel<<<dim3(Bb, Zz / 64, 4), 256, 0, stream>>>(
            xa, c2v, tot, out + (size_t)it * Bb * Zz * Nn,
            vn_deg, voff, (it != ITERS - 1) ? 1 : 0);
    }
}